// Round 1
// baseline (3709.636 us; speedup 1.0000x reference)
//
#include <hip/hip_runtime.h>
#include <math.h>

#define BATCH 2048

__device__ __forceinline__ float fsign(float v) {
    return v > 0.f ? 1.f : (v < 0.f ? -1.f : 0.f);
}

__global__ void binarize_k(const float* __restrict__ w, signed char* __restrict__ o, int n) {
    int i = blockIdx.x * 256 + threadIdx.x;
    if (i < n) {
        float v = w[i];
        o[i] = v > 0.f ? 1 : (v < 0.f ? -1 : 0);
    }
}

// K1: conv1(1->32,k3,p0) + bias + BN + sign + pool2 -> act1 [B,32,13,13] int8
__global__ void k1_conv1(const float* __restrict__ x, const float* __restrict__ w1,
                         const float* __restrict__ b1, const float* __restrict__ g1,
                         const float* __restrict__ be1, const float* __restrict__ m1,
                         const float* __restrict__ v1, signed char* __restrict__ act1) {
    int t = blockIdx.x * 256 + threadIdx.x;
    if (t >= BATCH * 32 * 13 * 13) return;
    int px = t % 13, py = (t / 13) % 13, oc = (t / 169) % 32, b = t / (169 * 32);
    float sw[9];
#pragma unroll
    for (int i = 0; i < 9; i++) sw[i] = fsign(w1[oc * 9 + i]);
    float bias = b1[oc], m = m1[oc];
    float sc = g1[oc] / sqrtf(v1[oc] + 1e-5f), bb = be1[oc];
    const float* xb = x + b * 784;
    float best = -2.f;
#pragma unroll
    for (int dy = 0; dy < 2; dy++)
#pragma unroll
        for (int dx = 0; dx < 2; dx++) {
            int oy = 2 * py + dy, ox = 2 * px + dx;
            float acc = 0.f;
#pragma unroll
            for (int ky = 0; ky < 3; ky++)
#pragma unroll
                for (int kx = 0; kx < 3; kx++)
                    acc += xb[(oy + ky) * 28 + ox + kx] * sw[ky * 3 + kx];
            float z = acc + bias;
            float bn = (z - m) * sc + bb;   // sign(clip(bn)) == sign(bn)
            best = fmaxf(best, fsign(bn));
        }
    act1[t] = (signed char)best;
}

// K2: conv2(32->64,k5,p2) + bias + BN + sign + pool2 -> act2 [B,64,6,6] int8
__global__ void k2_conv2(const signed char* __restrict__ act1, const signed char* __restrict__ sw2,
                         const float* __restrict__ b2, const float* __restrict__ g2,
                         const float* __restrict__ be2, const float* __restrict__ m2,
                         const float* __restrict__ v2, signed char* __restrict__ act2) {
    __shared__ signed char w[800];
    int oc = blockIdx.y;
    for (int i = threadIdx.x; i < 800; i += 256) w[i] = sw2[oc * 800 + i];
    __syncthreads();
    int t = blockIdx.x * 256 + threadIdx.x;
    if (t >= BATCH * 36) return;
    int p = t % 36, b = t / 36;
    int py = p / 6, px = p % 6;
    int acc0 = 0, acc1 = 0, acc2 = 0, acc3 = 0;
    int iy0 = 2 * py - 2, ix0 = 2 * px - 2;
    for (int ic = 0; ic < 32; ic++) {
        int pa[36];
        const signed char* a = act1 + (b * 32 + ic) * 169;
#pragma unroll
        for (int r = 0; r < 6; r++) {
            int iy = iy0 + r;
            bool vy = (iy >= 0) && (iy < 13);
#pragma unroll
            for (int c = 0; c < 6; c++) {
                int ix = ix0 + c;
                pa[r * 6 + c] = (vy && ix >= 0 && ix < 13) ? (int)a[iy * 13 + ix] : 0;
            }
        }
        const signed char* ww = w + ic * 25;
#pragma unroll
        for (int ky = 0; ky < 5; ky++)
#pragma unroll
            for (int kx = 0; kx < 5; kx++) {
                int wv = (int)ww[ky * 5 + kx];
                acc0 += pa[ky * 6 + kx] * wv;
                acc1 += pa[ky * 6 + kx + 1] * wv;
                acc2 += pa[(ky + 1) * 6 + kx] * wv;
                acc3 += pa[(ky + 1) * 6 + kx + 1] * wv;
            }
    }
    float bias = b2[oc], m = m2[oc];
    float sc = g2[oc] / sqrtf(v2[oc] + 1e-5f), bb = be2[oc];
    float best = -2.f;
    int accs[4] = {acc0, acc1, acc2, acc3};
#pragma unroll
    for (int q = 0; q < 4; q++) {
        float z = (float)accs[q] + bias;
        float bn = (z - m) * sc + bb;
        best = fmaxf(best, fsign(bn));
    }
    act2[(b * 64 + oc) * 36 + p] = (signed char)best;
}

// K3: fc1 (2304->1024) + bias + BN + sign -> act3 [B,1024] int8
__global__ void k3_fc1(const signed char* __restrict__ act2, const signed char* __restrict__ swf1,
                       const float* __restrict__ bf1, const float* __restrict__ gf1,
                       const float* __restrict__ bef1, const float* __restrict__ mf1,
                       const float* __restrict__ vf1, signed char* __restrict__ act3) {
    int o = blockIdx.x * 256 + threadIdx.x;  // 0..1023
    int b = blockIdx.y;
    const signed char* h = act2 + b * 2304;
    const signed char* w = swf1 + o * 2304;
    int acc = 0;
#pragma unroll 8
    for (int k = 0; k < 2304; k++) acc += (int)h[k] * (int)w[k];
    float z = (float)acc + bf1[o];
    float bn = (z - mf1[o]) * (gf1[o] / sqrtf(vf1[o] + 1e-5f)) + bef1[o];
    act3[b * 1024 + o] = (signed char)fsign(bn);
}

// K4: fc2 (1024->10) + bias + BN + log_softmax -> out [B,10] f32. One wave per image.
__global__ void k4_fc2(const signed char* __restrict__ act3, const signed char* __restrict__ swf2,
                       const float* __restrict__ bf2, const float* __restrict__ gf2,
                       const float* __restrict__ bef2, const float* __restrict__ mf2,
                       const float* __restrict__ vf2, float* __restrict__ out) {
    int wid = (blockIdx.x * 256 + threadIdx.x) >> 6;
    int lane = threadIdx.x & 63;
    if (wid >= BATCH) return;
    const signed char* h = act3 + wid * 1024;
    int acc[10];
#pragma unroll
    for (int o = 0; o < 10; o++) acc[o] = 0;
    for (int k = lane; k < 1024; k += 64) {
        int a = (int)h[k];
#pragma unroll
        for (int o = 0; o < 10; o++) acc[o] += a * (int)swf2[o * 1024 + k];
    }
#pragma unroll
    for (int o = 0; o < 10; o++)
        for (int s = 32; s > 0; s >>= 1) acc[o] += __shfl_xor(acc[o], s);
    if (lane == 0) {
        float logit[10];
        float mx = -1e30f;
#pragma unroll
        for (int o = 0; o < 10; o++) {
            float z = (float)acc[o] + bf2[o];
            float bn = (z - mf2[o]) * (gf2[o] / sqrtf(vf2[o] + 1e-5f)) + bef2[o];
            logit[o] = bn;
            mx = fmaxf(mx, bn);
        }
        float s = 0.f;
#pragma unroll
        for (int o = 0; o < 10; o++) s += expf(logit[o] - mx);
        float lse = mx + logf(s);
#pragma unroll
        for (int o = 0; o < 10; o++) out[wid * 10 + o] = logit[o] - lse;
    }
}

extern "C" void kernel_launch(void* const* d_in, const int* in_sizes, int n_in,
                              void* d_out, int out_size, void* d_ws, size_t ws_size,
                              hipStream_t stream) {
    const float* x   = (const float*)d_in[0];
    const float* w1  = (const float*)d_in[1];
    const float* b1  = (const float*)d_in[2];
    const float* g1  = (const float*)d_in[3];
    const float* be1 = (const float*)d_in[4];
    const float* m1  = (const float*)d_in[5];
    const float* v1  = (const float*)d_in[6];
    const float* w2  = (const float*)d_in[7];
    const float* b2  = (const float*)d_in[8];
    const float* g2  = (const float*)d_in[9];
    const float* be2 = (const float*)d_in[10];
    const float* m2  = (const float*)d_in[11];
    const float* v2  = (const float*)d_in[12];
    const float* wf1 = (const float*)d_in[13];
    const float* bf1 = (const float*)d_in[14];
    const float* gf1 = (const float*)d_in[15];
    const float* bef1= (const float*)d_in[16];
    const float* mf1 = (const float*)d_in[17];
    const float* vf1 = (const float*)d_in[18];
    const float* wf2 = (const float*)d_in[19];
    const float* bf2 = (const float*)d_in[20];
    const float* gf2 = (const float*)d_in[21];
    const float* bef2= (const float*)d_in[22];
    const float* mf2 = (const float*)d_in[23];
    const float* vf2 = (const float*)d_in[24];
    float* out = (float*)d_out;

    // ws layout (all int8)
    char* ws = (char*)d_ws;
    signed char* act1 = (signed char*)ws;                  // 2048*32*169   = 11,085,824
    signed char* act2 = act1 + 11085824;                   // 2048*2304     =  4,718,592
    signed char* act3 = act2 + 4718592;                    // 2048*1024     =  2,097,152
    signed char* sw2  = act3 + 2097152;                    // 64*800        =     51,200
    signed char* swf1 = sw2 + 51200;                       // 1024*2304     =  2,359,296
    signed char* swf2 = swf1 + 2359296;                    // 10*1024       =     10,240

    binarize_k<<<(51200 + 255) / 256, 256, 0, stream>>>(w2, sw2, 51200);
    binarize_k<<<(2359296 + 255) / 256, 256, 0, stream>>>(wf1, swf1, 2359296);
    binarize_k<<<(10240 + 255) / 256, 256, 0, stream>>>(wf2, swf2, 10240);

    int n1 = BATCH * 32 * 13 * 13;
    k1_conv1<<<(n1 + 255) / 256, 256, 0, stream>>>(x, w1, b1, g1, be1, m1, v1, act1);

    dim3 g2d((BATCH * 36 + 255) / 256, 64);
    k2_conv2<<<g2d, 256, 0, stream>>>(act1, sw2, b2, g2, be2, m2, v2, act2);

    dim3 g3d(4, BATCH);
    k3_fc1<<<g3d, 256, 0, stream>>>(act2, swf1, bf1, gf1, bef1, mf1, vf1, act3);

    k4_fc2<<<(BATCH * 64 + 255) / 256, 256, 0, stream>>>(act3, swf2, bf2, gf2, bef2, mf2, vf2, out);
}

// Round 3
// 322.948 us; speedup vs baseline: 11.4868x; 11.4868x over previous
//
#include <hip/hip_runtime.h>
#include <math.h>

#define BATCH 2048

__device__ __forceinline__ int sdot4(int a, int b, int c) {
    return __builtin_amdgcn_sdot4(a, b, c, false);
}

__device__ __forceinline__ float fsign(float v) {
    return v > 0.f ? 1.f : (v < 0.f ? -1.f : 0.f);
}

__global__ void binarize_k(const float* __restrict__ w, signed char* __restrict__ o, int n) {
    int i = blockIdx.x * 256 + threadIdx.x;
    if (i < n) {
        float v = w[i];
        o[i] = v > 0.f ? 1 : (v < 0.f ? -1 : 0);
    }
}

// w2 [64][32][5][5] -> w2p [64][25][32] int8 (sign)
__global__ void pack_w2_k(const float* __restrict__ w2, signed char* __restrict__ w2p) {
    int i = blockIdx.x * 256 + threadIdx.x;  // 51200
    int ic = i % 32, tap = (i / 32) % 25, oc = i / 800;
    float v = w2[(oc * 32 + ic) * 25 + tap];
    w2p[i] = v > 0.f ? 1 : (v < 0.f ? -1 : 0);
}

// wf1 [1024][2304] -> wf1p dword layout [576 k4][1024 o], byte j of dword = k4*4+j
__global__ void pack_wf1_k(const float* __restrict__ wf1, signed char* __restrict__ wf1p) {
    int i = blockIdx.x * 256 + threadIdx.x;  // 2359296 bytes
    int j = i & 3, d = i >> 2;
    int o = d % 1024, k4 = d / 1024;
    float v = wf1[o * 2304 + k4 * 4 + j];
    wf1p[i] = v > 0.f ? 1 : (v < 0.f ? -1 : 0);
}

// K1: conv1 + bias + BN + sign + pool2 -> act1 channel-last [B][13][13][32] int8
__global__ void k1_conv1(const float* __restrict__ x, const float* __restrict__ w1,
                         const float* __restrict__ b1, const float* __restrict__ g1,
                         const float* __restrict__ be1, const float* __restrict__ m1,
                         const float* __restrict__ v1, signed char* __restrict__ act1) {
    int t = blockIdx.x * 256 + threadIdx.x;  // 2048*169
    if (t >= BATCH * 169) return;
    int px = t % 13, py = (t / 13) % 13, b = t / 169;
    const float* xb = x + b * 784;
    float xr[4][4];
    int oy0 = 2 * py, ox0 = 2 * px;
#pragma unroll
    for (int dy = 0; dy < 4; dy++)
#pragma unroll
        for (int dx = 0; dx < 4; dx++) xr[dy][dx] = xb[(oy0 + dy) * 28 + ox0 + dx];
    int dws[8];
#pragma unroll
    for (int j = 0; j < 8; j++) {
        int dw = 0;
#pragma unroll
        for (int jj = 0; jj < 4; jj++) {
            int oc = j * 4 + jj;
            float sw[9];
#pragma unroll
            for (int i = 0; i < 9; i++) sw[i] = fsign(w1[oc * 9 + i]);
            float bias = b1[oc], m = m1[oc];
            float sc = g1[oc] / sqrtf(v1[oc] + 1e-5f), bb = be1[oc];
            float best = -2.f;
#pragma unroll
            for (int dy = 0; dy < 2; dy++)
#pragma unroll
                for (int dx = 0; dx < 2; dx++) {
                    float acc = 0.f;
#pragma unroll
                    for (int ky = 0; ky < 3; ky++)
#pragma unroll
                        for (int kx = 0; kx < 3; kx++)
                            acc += xr[dy + ky][dx + kx] * sw[ky * 3 + kx];
                    float bn = (acc + bias - m) * sc + bb;
                    best = fmaxf(best, fsign(bn));
                }
            dw |= ((int)best & 0xFF) << (8 * jj);
        }
        dws[j] = dw;
    }
    int4* dst = (int4*)(act1 + (size_t)t * 32);
    dst[0] = make_int4(dws[0], dws[1], dws[2], dws[3]);
    dst[1] = make_int4(dws[4], dws[5], dws[6], dws[7]);
}

// K2: conv2(32->64,k5,p2) + bias + BN + sign + pool2 -> act2 [B][64][36] int8
#define OCB 4
__global__ __launch_bounds__(256) void k2_conv2(
        const signed char* __restrict__ act1, const signed char* __restrict__ w2p,
        const float* __restrict__ b2, const float* __restrict__ g2,
        const float* __restrict__ be2, const float* __restrict__ m2,
        const float* __restrict__ v2, signed char* __restrict__ act2) {
    __shared__ int4 wlds[OCB * 25 * 2];  // [oj][tap][half], 16B each
    int oc0 = blockIdx.y * OCB;
    {
        const int4* wsrc = (const int4*)(w2p + oc0 * 800);
        for (int i = threadIdx.x; i < OCB * 50; i += 256) wlds[i] = wsrc[i];
    }
    __syncthreads();
    int idx = blockIdx.x * 256 + threadIdx.x;  // 2048*36 exactly
    int b = idx / 36, p = idx % 36;
    int py = p / 6, px = p % 6;
    int iy0 = 2 * py - 2, ix0 = 2 * px - 2;
    int acc[2][2][OCB];
#pragma unroll
    for (int dy = 0; dy < 2; dy++)
#pragma unroll
        for (int dx = 0; dx < 2; dx++)
#pragma unroll
            for (int oj = 0; oj < OCB; oj++) acc[dy][dx][oj] = 0;
    const int4* base = (const int4*)(act1 + (size_t)b * 169 * 32);
#pragma unroll 1
    for (int half = 0; half < 2; half++) {
        int4 pa[36];
#pragma unroll
        for (int r = 0; r < 6; r++) {
            int iy = iy0 + r;
            bool vy = (iy >= 0) && (iy < 13);
#pragma unroll
            for (int c = 0; c < 6; c++) {
                int ix = ix0 + c;
                if (vy && ix >= 0 && ix < 13)
                    pa[r * 6 + c] = base[(iy * 13 + ix) * 2 + half];
                else
                    pa[r * 6 + c] = make_int4(0, 0, 0, 0);
            }
        }
#pragma unroll
        for (int oj = 0; oj < OCB; oj++) {
#pragma unroll
            for (int tap = 0; tap < 25; tap++) {
                int4 wv = wlds[(oj * 25 + tap) * 2 + half];
                int ky = tap / 5, kx = tap % 5;
#pragma unroll
                for (int dy = 0; dy < 2; dy++)
#pragma unroll
                    for (int dx = 0; dx < 2; dx++) {
                        int pi = (ky + dy) * 6 + kx + dx;
                        int a0 = acc[dy][dx][oj];
                        a0 = sdot4(pa[pi].x, wv.x, a0);
                        a0 = sdot4(pa[pi].y, wv.y, a0);
                        a0 = sdot4(pa[pi].z, wv.z, a0);
                        a0 = sdot4(pa[pi].w, wv.w, a0);
                        acc[dy][dx][oj] = a0;
                    }
            }
        }
    }
#pragma unroll
    for (int oj = 0; oj < OCB; oj++) {
        int oc = oc0 + oj;
        float bias = b2[oc], m = m2[oc];
        float sc = g2[oc] / sqrtf(v2[oc] + 1e-5f), bb = be2[oc];
        float best = -2.f;
#pragma unroll
        for (int dy = 0; dy < 2; dy++)
#pragma unroll
            for (int dx = 0; dx < 2; dx++) {
                float bn = ((float)acc[dy][dx][oj] + bias - m) * sc + bb;
                best = fmaxf(best, fsign(bn));
            }
        act2[((size_t)b * 64 + oc) * 36 + p] = (signed char)best;
    }
}

// K3: fc1 (2304->1024) + bias + BN + sign -> act3 [B][1024] int8. 8 images/block.
__global__ void k3_fc1(const signed char* __restrict__ act2, const signed char* __restrict__ wf1p,
                       const float* __restrict__ bf1, const float* __restrict__ gf1,
                       const float* __restrict__ bef1, const float* __restrict__ mf1,
                       const float* __restrict__ vf1, signed char* __restrict__ act3) {
    int o = blockIdx.x * 256 + threadIdx.x;  // grid.x=4 -> 0..1023
    int b0 = blockIdx.y * 8;
    const int* wp = (const int*)wf1p;
    const int4* h4 = (const int4*)act2;  // [b][144]
    int acc[8];
#pragma unroll
    for (int i = 0; i < 8; i++) acc[i] = 0;
    for (int k16 = 0; k16 < 144; k16++) {
        int4 hv[8];
#pragma unroll
        for (int i = 0; i < 8; i++) hv[i] = h4[(size_t)(b0 + i) * 144 + k16];
        int w0 = wp[(k16 * 4 + 0) * 1024 + o];
        int w1 = wp[(k16 * 4 + 1) * 1024 + o];
        int w2 = wp[(k16 * 4 + 2) * 1024 + o];
        int w3 = wp[(k16 * 4 + 3) * 1024 + o];
#pragma unroll
        for (int i = 0; i < 8; i++) {
            int a0 = acc[i];
            a0 = sdot4(hv[i].x, w0, a0);
            a0 = sdot4(hv[i].y, w1, a0);
            a0 = sdot4(hv[i].z, w2, a0);
            a0 = sdot4(hv[i].w, w3, a0);
            acc[i] = a0;
        }
    }
    float bias = bf1[o], m = mf1[o];
    float sc = gf1[o] / sqrtf(vf1[o] + 1e-5f), bb = bef1[o];
#pragma unroll
    for (int i = 0; i < 8; i++) {
        float bn = ((float)acc[i] + bias - m) * sc + bb;
        act3[(size_t)(b0 + i) * 1024 + o] = (signed char)fsign(bn);
    }
}

// K4: fc2 (1024->10) + bias + BN + log_softmax. One wave per image.
__global__ void k4_fc2(const signed char* __restrict__ act3, const signed char* __restrict__ swf2,
                       const float* __restrict__ bf2, const float* __restrict__ gf2,
                       const float* __restrict__ bef2, const float* __restrict__ mf2,
                       const float* __restrict__ vf2, float* __restrict__ out) {
    int wid = (blockIdx.x * 256 + threadIdx.x) >> 6;
    int lane = threadIdx.x & 63;
    if (wid >= BATCH) return;
    const int* hd = (const int*)act3 + (size_t)wid * 256;
    const int* wd = (const int*)swf2;  // [10][256] dwords
    int acc[10];
#pragma unroll
    for (int o = 0; o < 10; o++) acc[o] = 0;
#pragma unroll
    for (int i = 0; i < 4; i++) {
        int k4 = i * 64 + lane;
        int hv = hd[k4];
#pragma unroll
        for (int o = 0; o < 10; o++)
            acc[o] = sdot4(hv, wd[o * 256 + k4], acc[o]);
    }
#pragma unroll
    for (int o = 0; o < 10; o++)
#pragma unroll
        for (int s = 32; s > 0; s >>= 1) acc[o] += __shfl_xor(acc[o], s);
    if (lane == 0) {
        float logit[10];
        float mx = -1e30f;
#pragma unroll
        for (int o = 0; o < 10; o++) {
            float z = (float)acc[o] + bf2[o];
            float bn = (z - mf2[o]) * (gf2[o] / sqrtf(vf2[o] + 1e-5f)) + bef2[o];
            logit[o] = bn;
            mx = fmaxf(mx, bn);
        }
        float s = 0.f;
#pragma unroll
        for (int o = 0; o < 10; o++) s += expf(logit[o] - mx);
        float lse = mx + logf(s);
#pragma unroll
        for (int o = 0; o < 10; o++) out[(size_t)wid * 10 + o] = logit[o] - lse;
    }
}

extern "C" void kernel_launch(void* const* d_in, const int* in_sizes, int n_in,
                              void* d_out, int out_size, void* d_ws, size_t ws_size,
                              hipStream_t stream) {
    const float* x   = (const float*)d_in[0];
    const float* w1  = (const float*)d_in[1];
    const float* b1  = (const float*)d_in[2];
    const float* g1  = (const float*)d_in[3];
    const float* be1 = (const float*)d_in[4];
    const float* m1  = (const float*)d_in[5];
    const float* v1  = (const float*)d_in[6];
    const float* w2  = (const float*)d_in[7];
    const float* b2  = (const float*)d_in[8];
    const float* g2  = (const float*)d_in[9];
    const float* be2 = (const float*)d_in[10];
    const float* m2  = (const float*)d_in[11];
    const float* v2  = (const float*)d_in[12];
    const float* wf1 = (const float*)d_in[13];
    const float* bf1 = (const float*)d_in[14];
    const float* gf1 = (const float*)d_in[15];
    const float* bef1= (const float*)d_in[16];
    const float* mf1 = (const float*)d_in[17];
    const float* vf1 = (const float*)d_in[18];
    const float* wf2 = (const float*)d_in[19];
    const float* bf2 = (const float*)d_in[20];
    const float* gf2 = (const float*)d_in[21];
    const float* bef2= (const float*)d_in[22];
    const float* mf2 = (const float*)d_in[23];
    const float* vf2 = (const float*)d_in[24];
    float* out = (float*)d_out;

    // ws layout (all int8)
    char* ws = (char*)d_ws;
    signed char* act1 = (signed char*)ws;                  // 2048*169*32   = 11,075,584
    signed char* act2 = act1 + 11075584;                   // 2048*2304     =  4,718,592
    signed char* act3 = act2 + 4718592;                    // 2048*1024     =  2,097,152
    signed char* w2p  = act3 + 2097152;                    // 64*25*32      =     51,200
    signed char* wf1p = w2p + 51200;                       // 2,359,296
    signed char* wf2p = wf1p + 2359296;                    // 10,240

    pack_w2_k<<<200, 256, 0, stream>>>(w2, w2p);
    pack_wf1_k<<<9216, 256, 0, stream>>>(wf1, wf1p);
    binarize_k<<<40, 256, 0, stream>>>(wf2, wf2p, 10240);

    k1_conv1<<<1352, 256, 0, stream>>>(x, w1, b1, g1, be1, m1, v1, act1);

    dim3 g2d(288, 64 / OCB);
    k2_conv2<<<g2d, 256, 0, stream>>>(act1, w2p, b2, g2, be2, m2, v2, act2);

    dim3 g3d(4, 256);
    k3_fc1<<<g3d, 256, 0, stream>>>(act2, wf1p, bf1, gf1, bef1, mf1, vf1, act3);

    k4_fc2<<<512, 256, 0, stream>>>(act3, wf2p, bf2, gf2, bef2, mf2, vf2, out);
}

// Round 4
// 189.770 us; speedup vs baseline: 19.5481x; 1.7018x over previous
//
#include <hip/hip_runtime.h>
#include <math.h>

#define BATCH 2048

typedef __attribute__((ext_vector_type(4))) int i32x4;
typedef __attribute__((ext_vector_type(16))) int i32x16;

__device__ __forceinline__ int sdot4(int a, int b, int c) {
    return __builtin_amdgcn_sdot4(a, b, c, false);
}

__device__ __forceinline__ float fsign(float v) {
    return v > 0.f ? 1.f : (v < 0.f ? -1.f : 0.f);
}

__global__ void binarize_k(const float* __restrict__ w, signed char* __restrict__ o, int n) {
    int i = blockIdx.x * 256 + threadIdx.x;
    if (i < n) {
        float v = w[i];
        o[i] = v > 0.f ? 1 : (v < 0.f ? -1 : 0);
    }
}

// w2 [64][32][5][5] -> w2p [64][25][32] int8 (sign)
__global__ void pack_w2_k(const float* __restrict__ w2, signed char* __restrict__ w2p) {
    int i = blockIdx.x * 256 + threadIdx.x;  // 51200
    int ic = i % 32, tap = (i / 32) % 25, oc = i / 800;
    float v = w2[(oc * 32 + ic) * 25 + tap];
    w2p[i] = v > 0.f ? 1 : (v < 0.f ? -1 : 0);
}

// wf1 [1024][2304] -> wf1p dword layout [576 k4][1024 o]
__global__ void pack_wf1_k(const float* __restrict__ wf1, signed char* __restrict__ wf1p) {
    int i = blockIdx.x * 256 + threadIdx.x;  // 2359296 bytes
    int j = i & 3, d = i >> 2;
    int o = d % 1024, k4 = d / 1024;
    float v = wf1[o * 2304 + k4 * 4 + j];
    wf1p[i] = v > 0.f ? 1 : (v < 0.f ? -1 : 0);
}

// K1: conv1 + bias + BN + sign + pool2 -> act1 channel-last [B][13][13][32] int8
__global__ void k1_conv1(const float* __restrict__ x, const float* __restrict__ w1,
                         const float* __restrict__ b1, const float* __restrict__ g1,
                         const float* __restrict__ be1, const float* __restrict__ m1,
                         const float* __restrict__ v1, signed char* __restrict__ act1) {
    int t = blockIdx.x * 256 + threadIdx.x;  // 2048*169
    if (t >= BATCH * 169) return;
    int px = t % 13, py = (t / 13) % 13, b = t / 169;
    const float* xb = x + b * 784;
    float xr[4][4];
    int oy0 = 2 * py, ox0 = 2 * px;
#pragma unroll
    for (int dy = 0; dy < 4; dy++)
#pragma unroll
        for (int dx = 0; dx < 4; dx++) xr[dy][dx] = xb[(oy0 + dy) * 28 + ox0 + dx];
    int dws[8];
#pragma unroll
    for (int j = 0; j < 8; j++) {
        int dw = 0;
#pragma unroll
        for (int jj = 0; jj < 4; jj++) {
            int oc = j * 4 + jj;
            float sw[9];
#pragma unroll
            for (int i = 0; i < 9; i++) sw[i] = fsign(w1[oc * 9 + i]);
            float bias = b1[oc], m = m1[oc];
            float sc = g1[oc] / sqrtf(v1[oc] + 1e-5f), bb = be1[oc];
            float best = -2.f;
#pragma unroll
            for (int dy = 0; dy < 2; dy++)
#pragma unroll
                for (int dx = 0; dx < 2; dx++) {
                    float acc = 0.f;
#pragma unroll
                    for (int ky = 0; ky < 3; ky++)
#pragma unroll
                        for (int kx = 0; kx < 3; kx++)
                            acc += xr[dy + ky][dx + kx] * sw[ky * 3 + kx];
                    float bn = (acc + bias - m) * sc + bb;
                    best = fmaxf(best, fsign(bn));
                }
            dw |= ((int)best & 0xFF) << (8 * jj);
        }
        dws[j] = dw;
    }
    int4* dst = (int4*)(act1 + (size_t)t * 32);
    dst[0] = make_int4(dws[0], dws[1], dws[2], dws[3]);
    dst[1] = make_int4(dws[4], dws[5], dws[6], dws[7]);
}

// K2: conv2 as implicit-GEMM MFMA i8. Block = 2 images, 9 waves.
// LDS: act1 padded [2][17*17*32] (zero border) + weights [25 tap][64 oc][32 ic]
#define K2_IMG_STRIDE 9248          // 17*17*32
#define K2_WOFF 18496               // 2*9248
__device__ __forceinline__ void k2_epilogue(i32x16 A, int oc, int wave, int kh, int b0,
                                            const float* __restrict__ b2,
                                            const float* __restrict__ g2,
                                            const float* __restrict__ be2,
                                            const float* __restrict__ m2,
                                            const float* __restrict__ v2,
                                            signed char* __restrict__ act2) {
    float bias = b2[oc], mm = m2[oc];
    float sc = g2[oc] / sqrtf(v2[oc] + 1e-5f), bb = be2[oc];
#pragma unroll
    for (int g = 0; g < 4; g++) {
        int qo = wave * 8 + kh + 2 * g;      // 0..71 pool cell (2 images)
        int imo = qo / 36, qqo = qo - imo * 36;
        float best = -2.f;
#pragma unroll
        for (int jj = 0; jj < 4; jj++) {     // 4 pool partners live in reg quad
            float z = (float)A[g * 4 + jj] + bias;
            float bn = (z - mm) * sc + bb;
            best = fmaxf(best, fsign(bn));
        }
        act2[((size_t)(b0 + imo) * 64 + oc) * 36 + qqo] = (signed char)best;
    }
}

__global__ __launch_bounds__(576) void k2_mfma(
        const signed char* __restrict__ act1, const signed char* __restrict__ w2p,
        const float* __restrict__ b2, const float* __restrict__ g2,
        const float* __restrict__ be2, const float* __restrict__ m2,
        const float* __restrict__ v2, signed char* __restrict__ act2) {
    __shared__ __align__(16) signed char smem[69696];  // 18496 + 51200
    int tid = threadIdx.x;
    int b0 = blockIdx.x * 2;
    i32x4* s4 = (i32x4*)smem;
    // zero the padded activation region (borders must be 0)
    i32x4 z4 = {0, 0, 0, 0};
    for (int i = tid; i < 1156; i += 576) s4[i] = z4;
    __syncthreads();
    // interior pixels: global act1 [b][169][32] -> padded LDS [(y+2)*17+(x+2)]*32
    {
        const i32x4* src = (const i32x4*)(act1 + (size_t)b0 * 5408);
        for (int i = tid; i < 676; i += 576) {
            int im = i / 338, r = i - im * 338;
            int pix = r >> 1, half = r & 1;
            int yy = pix / 13 + 2, xx = pix % 13 + 2;
            *(i32x4*)(smem + im * K2_IMG_STRIDE + (yy * 17 + xx) * 32 + half * 16) = src[i];
        }
        // weights: w2p [oc][25 tap][32 ic] -> LDS [tap][oc][32 ic]
        const i32x4* wsrc = (const i32x4*)w2p;
        for (int i = tid; i < 3200; i += 576) {
            int oc = i / 50, r = i - oc * 50;
            int tap = r >> 1, half = r & 1;
            *(i32x4*)(smem + K2_WOFF + tap * 2048 + oc * 32 + half * 16) = wsrc[i];
        }
    }
    __syncthreads();

    int wave = tid >> 6, lane = tid & 63;
    int lrow = lane & 31, kh = lane >> 5;
    // A-row m = wave*32+lrow, pool-ordered: m = 4*q + j
    int m = wave * 32 + lrow;
    int q = m >> 2, j = m & 3;
    int img = q / 36, qq = q - img * 36;
    int oy = 2 * (qq / 6) + (j >> 1);
    int ox = 2 * (qq - (qq / 6) * 6) + (j & 1);
    const signed char* abase = smem + img * K2_IMG_STRIDE + (oy * 17 + ox) * 32 + kh * 16;
    const signed char* bbase = smem + K2_WOFF + lrow * 32 + kh * 16;

    i32x16 acc0 = {0};
    i32x16 acc1 = {0};
#pragma unroll 5
    for (int tap = 0; tap < 25; ++tap) {
        int ky = tap / 5, kx = tap - (tap / 5) * 5;
        i32x4 a = *(const i32x4*)(abase + (ky * 17 + kx) * 32);
        i32x4 w0 = *(const i32x4*)(bbase + tap * 2048);
        i32x4 w1 = *(const i32x4*)(bbase + tap * 2048 + 1024);
        acc0 = __builtin_amdgcn_mfma_i32_32x32x32_i8(a, w0, acc0, 0, 0, 0);
        acc1 = __builtin_amdgcn_mfma_i32_32x32x32_i8(a, w1, acc1, 0, 0, 0);
    }
    k2_epilogue(acc0, lrow,      wave, kh, b0, b2, g2, be2, m2, v2, act2);
    k2_epilogue(acc1, 32 + lrow, wave, kh, b0, b2, g2, be2, m2, v2, act2);
}

// K3: fc1 (2304->1024) + bias + BN + sign -> act3 [B][1024] int8. 8 images/block.
__global__ void k3_fc1(const signed char* __restrict__ act2, const signed char* __restrict__ wf1p,
                       const float* __restrict__ bf1, const float* __restrict__ gf1,
                       const float* __restrict__ bef1, const float* __restrict__ mf1,
                       const float* __restrict__ vf1, signed char* __restrict__ act3) {
    int o = blockIdx.x * 256 + threadIdx.x;
    int b0 = blockIdx.y * 8;
    const int* wp = (const int*)wf1p;
    const int4* h4 = (const int4*)act2;
    int acc[8];
#pragma unroll
    for (int i = 0; i < 8; i++) acc[i] = 0;
    for (int k16 = 0; k16 < 144; k16++) {
        int4 hv[8];
#pragma unroll
        for (int i = 0; i < 8; i++) hv[i] = h4[(size_t)(b0 + i) * 144 + k16];
        int w0 = wp[(k16 * 4 + 0) * 1024 + o];
        int w1 = wp[(k16 * 4 + 1) * 1024 + o];
        int w2 = wp[(k16 * 4 + 2) * 1024 + o];
        int w3 = wp[(k16 * 4 + 3) * 1024 + o];
#pragma unroll
        for (int i = 0; i < 8; i++) {
            int a0 = acc[i];
            a0 = sdot4(hv[i].x, w0, a0);
            a0 = sdot4(hv[i].y, w1, a0);
            a0 = sdot4(hv[i].z, w2, a0);
            a0 = sdot4(hv[i].w, w3, a0);
            acc[i] = a0;
        }
    }
    float bias = bf1[o], m = mf1[o];
    float sc = gf1[o] / sqrtf(vf1[o] + 1e-5f), bb = bef1[o];
#pragma unroll
    for (int i = 0; i < 8; i++) {
        float bn = ((float)acc[i] + bias - m) * sc + bb;
        act3[(size_t)(b0 + i) * 1024 + o] = (signed char)fsign(bn);
    }
}

// K4: fc2 (1024->10) + bias + BN + log_softmax. One wave per image.
__global__ void k4_fc2(const signed char* __restrict__ act3, const signed char* __restrict__ swf2,
                       const float* __restrict__ bf2, const float* __restrict__ gf2,
                       const float* __restrict__ bef2, const float* __restrict__ mf2,
                       const float* __restrict__ vf2, float* __restrict__ out) {
    int wid = (blockIdx.x * 256 + threadIdx.x) >> 6;
    int lane = threadIdx.x & 63;
    if (wid >= BATCH) return;
    const int* hd = (const int*)act3 + (size_t)wid * 256;
    const int* wd = (const int*)swf2;
    int acc[10];
#pragma unroll
    for (int o = 0; o < 10; o++) acc[o] = 0;
#pragma unroll
    for (int i = 0; i < 4; i++) {
        int k4 = i * 64 + lane;
        int hv = hd[k4];
#pragma unroll
        for (int o = 0; o < 10; o++)
            acc[o] = sdot4(hv, wd[o * 256 + k4], acc[o]);
    }
#pragma unroll
    for (int o = 0; o < 10; o++)
#pragma unroll
        for (int s = 32; s > 0; s >>= 1) acc[o] += __shfl_xor(acc[o], s);
    if (lane == 0) {
        float logit[10];
        float mx = -1e30f;
#pragma unroll
        for (int o = 0; o < 10; o++) {
            float z = (float)acc[o] + bf2[o];
            float bn = (z - mf2[o]) * (gf2[o] / sqrtf(vf2[o] + 1e-5f)) + bef2[o];
            logit[o] = bn;
            mx = fmaxf(mx, bn);
        }
        float s = 0.f;
#pragma unroll
        for (int o = 0; o < 10; o++) s += expf(logit[o] - mx);
        float lse = mx + logf(s);
#pragma unroll
        for (int o = 0; o < 10; o++) out[(size_t)wid * 10 + o] = logit[o] - lse;
    }
}

extern "C" void kernel_launch(void* const* d_in, const int* in_sizes, int n_in,
                              void* d_out, int out_size, void* d_ws, size_t ws_size,
                              hipStream_t stream) {
    const float* x   = (const float*)d_in[0];
    const float* w1  = (const float*)d_in[1];
    const float* b1  = (const float*)d_in[2];
    const float* g1  = (const float*)d_in[3];
    const float* be1 = (const float*)d_in[4];
    const float* m1  = (const float*)d_in[5];
    const float* v1  = (const float*)d_in[6];
    const float* w2  = (const float*)d_in[7];
    const float* b2  = (const float*)d_in[8];
    const float* g2  = (const float*)d_in[9];
    const float* be2 = (const float*)d_in[10];
    const float* m2  = (const float*)d_in[11];
    const float* v2  = (const float*)d_in[12];
    const float* wf1 = (const float*)d_in[13];
    const float* bf1 = (const float*)d_in[14];
    const float* gf1 = (const float*)d_in[15];
    const float* bef1= (const float*)d_in[16];
    const float* mf1 = (const float*)d_in[17];
    const float* vf1 = (const float*)d_in[18];
    const float* wf2 = (const float*)d_in[19];
    const float* bf2 = (const float*)d_in[20];
    const float* gf2 = (const float*)d_in[21];
    const float* bef2= (const float*)d_in[22];
    const float* mf2 = (const float*)d_in[23];
    const float* vf2 = (const float*)d_in[24];
    float* out = (float*)d_out;

    // ws layout (identical footprint to the passing round-3 layout)
    char* ws = (char*)d_ws;
    signed char* act1 = (signed char*)ws;                  // 2048*169*32   = 11,075,584
    signed char* act2 = act1 + 11075584;                   // 2048*2304     =  4,718,592
    signed char* act3 = act2 + 4718592;                    // 2048*1024     =  2,097,152
    signed char* w2p  = act3 + 2097152;                    // 64*25*32      =     51,200
    signed char* wf1p = w2p + 51200;                       // 2,359,296
    signed char* wf2p = wf1p + 2359296;                    // 10,240

    pack_w2_k<<<200, 256, 0, stream>>>(w2, w2p);
    pack_wf1_k<<<9216, 256, 0, stream>>>(wf1, wf1p);
    binarize_k<<<40, 256, 0, stream>>>(wf2, wf2p, 10240);

    k1_conv1<<<1352, 256, 0, stream>>>(x, w1, b1, g1, be1, m1, v1, act1);

    k2_mfma<<<1024, 576, 0, stream>>>(act1, w2p, b2, g2, be2, m2, v2, act2);

    dim3 g3d(4, 256);
    k3_fc1<<<g3d, 256, 0, stream>>>(act2, wf1p, bf1, gf1, bef1, mf1, vf1, act3);

    k4_fc2<<<512, 256, 0, stream>>>(act3, wf2p, bf2, gf2, bef2, mf2, vf2, out);
}

// Round 5
// 146.259 us; speedup vs baseline: 25.3634x; 1.2975x over previous
//
#include <hip/hip_runtime.h>
#include <math.h>

#define BATCH 2048

typedef __attribute__((ext_vector_type(4))) int i32x4;
typedef __attribute__((ext_vector_type(16))) int i32x16;

__device__ __forceinline__ int sdot4(int a, int b, int c) {
    return __builtin_amdgcn_sdot4(a, b, c, false);
}

__device__ __forceinline__ float fsign(float v) {
    return v > 0.f ? 1.f : (v < 0.f ? -1.f : 0.f);
}

__global__ void binarize_k(const float* __restrict__ w, signed char* __restrict__ o, int n) {
    int i = blockIdx.x * 256 + threadIdx.x;
    if (i < n) {
        float v = w[i];
        o[i] = v > 0.f ? 1 : (v < 0.f ? -1 : 0);
    }
}

// w2 [64][32][5][5] -> w2p [64][25][32] int8 (sign)
__global__ void pack_w2_k(const float* __restrict__ w2, signed char* __restrict__ w2p) {
    int i = blockIdx.x * 256 + threadIdx.x;  // 51200
    int ic = i % 32, tap = (i / 32) % 25, oc = i / 800;
    float v = w2[(oc * 32 + ic) * 25 + tap];
    w2p[i] = v > 0.f ? 1 : (v < 0.f ? -1 : 0);
}

// K1: conv1 + bias + BN + sign + pool2 -> act1 channel-last [B][13][13][32] int8
__global__ void k1_conv1(const float* __restrict__ x, const float* __restrict__ w1,
                         const float* __restrict__ b1, const float* __restrict__ g1,
                         const float* __restrict__ be1, const float* __restrict__ m1,
                         const float* __restrict__ v1, signed char* __restrict__ act1) {
    int t = blockIdx.x * 256 + threadIdx.x;  // 2048*169
    if (t >= BATCH * 169) return;
    int px = t % 13, py = (t / 13) % 13, b = t / 169;
    const float* xb = x + b * 784;
    float xr[4][4];
    int oy0 = 2 * py, ox0 = 2 * px;
#pragma unroll
    for (int dy = 0; dy < 4; dy++)
#pragma unroll
        for (int dx = 0; dx < 4; dx++) xr[dy][dx] = xb[(oy0 + dy) * 28 + ox0 + dx];
    int dws[8];
#pragma unroll
    for (int j = 0; j < 8; j++) {
        int dw = 0;
#pragma unroll
        for (int jj = 0; jj < 4; jj++) {
            int oc = j * 4 + jj;
            float sw[9];
#pragma unroll
            for (int i = 0; i < 9; i++) sw[i] = fsign(w1[oc * 9 + i]);
            float bias = b1[oc], m = m1[oc];
            float sc = g1[oc] / sqrtf(v1[oc] + 1e-5f), bb = be1[oc];
            float best = -2.f;
#pragma unroll
            for (int dy = 0; dy < 2; dy++)
#pragma unroll
                for (int dx = 0; dx < 2; dx++) {
                    float acc = 0.f;
#pragma unroll
                    for (int ky = 0; ky < 3; ky++)
#pragma unroll
                        for (int kx = 0; kx < 3; kx++)
                            acc += xr[dy + ky][dx + kx] * sw[ky * 3 + kx];
                    float bn = (acc + bias - m) * sc + bb;
                    best = fmaxf(best, fsign(bn));
                }
            dw |= ((int)best & 0xFF) << (8 * jj);
        }
        dws[j] = dw;
    }
    int4* dst = (int4*)(act1 + (size_t)t * 32);
    dst[0] = make_int4(dws[0], dws[1], dws[2], dws[3]);
    dst[1] = make_int4(dws[4], dws[5], dws[6], dws[7]);
}

// K2: conv2 as implicit-GEMM MFMA i8. Block = 2 images, 9 waves.
#define K2_IMG_STRIDE 9248          // 17*17*32
#define K2_WOFF 18496               // 2*9248
__device__ __forceinline__ void k2_epilogue(i32x16 A, int oc, int wave, int kh, int b0,
                                            const float* __restrict__ b2,
                                            const float* __restrict__ g2,
                                            const float* __restrict__ be2,
                                            const float* __restrict__ m2,
                                            const float* __restrict__ v2,
                                            signed char* __restrict__ act2) {
    float bias = b2[oc], mm = m2[oc];
    float sc = g2[oc] / sqrtf(v2[oc] + 1e-5f), bb = be2[oc];
#pragma unroll
    for (int g = 0; g < 4; g++) {
        int qo = wave * 8 + kh + 2 * g;      // 0..71 pool cell (2 images)
        int imo = qo / 36, qqo = qo - imo * 36;
        float best = -2.f;
#pragma unroll
        for (int jj = 0; jj < 4; jj++) {     // 4 pool partners live in reg quad
            float z = (float)A[g * 4 + jj] + bias;
            float bn = (z - mm) * sc + bb;
            best = fmaxf(best, fsign(bn));
        }
        act2[((size_t)(b0 + imo) * 64 + oc) * 36 + qqo] = (signed char)best;
    }
}

__global__ __launch_bounds__(576) void k2_mfma(
        const signed char* __restrict__ act1, const signed char* __restrict__ w2p,
        const float* __restrict__ b2, const float* __restrict__ g2,
        const float* __restrict__ be2, const float* __restrict__ m2,
        const float* __restrict__ v2, signed char* __restrict__ act2) {
    __shared__ __align__(16) signed char smem[69696];  // 18496 + 51200
    int tid = threadIdx.x;
    int b0 = blockIdx.x * 2;
    i32x4* s4 = (i32x4*)smem;
    i32x4 z4 = {0, 0, 0, 0};
    for (int i = tid; i < 1156; i += 576) s4[i] = z4;
    __syncthreads();
    {
        const i32x4* src = (const i32x4*)(act1 + (size_t)b0 * 5408);
        for (int i = tid; i < 676; i += 576) {
            int im = i / 338, r = i - im * 338;
            int pix = r >> 1, half = r & 1;
            int yy = pix / 13 + 2, xx = pix % 13 + 2;
            *(i32x4*)(smem + im * K2_IMG_STRIDE + (yy * 17 + xx) * 32 + half * 16) = src[i];
        }
        const i32x4* wsrc = (const i32x4*)w2p;
        for (int i = tid; i < 3200; i += 576) {
            int oc = i / 50, r = i - oc * 50;
            int tap = r >> 1, half = r & 1;
            *(i32x4*)(smem + K2_WOFF + tap * 2048 + oc * 32 + half * 16) = wsrc[i];
        }
    }
    __syncthreads();

    int wave = tid >> 6, lane = tid & 63;
    int lrow = lane & 31, kh = lane >> 5;
    int m = wave * 32 + lrow;
    int q = m >> 2, j = m & 3;
    int img = q / 36, qq = q - img * 36;
    int oy = 2 * (qq / 6) + (j >> 1);
    int ox = 2 * (qq - (qq / 6) * 6) + (j & 1);
    const signed char* abase = smem + img * K2_IMG_STRIDE + (oy * 17 + ox) * 32 + kh * 16;
    const signed char* bbase = smem + K2_WOFF + lrow * 32 + kh * 16;

    i32x16 acc0 = {0};
    i32x16 acc1 = {0};
#pragma unroll 5
    for (int tap = 0; tap < 25; ++tap) {
        int ky = tap / 5, kx = tap - (tap / 5) * 5;
        i32x4 a = *(const i32x4*)(abase + (ky * 17 + kx) * 32);
        i32x4 w0 = *(const i32x4*)(bbase + tap * 2048);
        i32x4 w1 = *(const i32x4*)(bbase + tap * 2048 + 1024);
        acc0 = __builtin_amdgcn_mfma_i32_32x32x32_i8(a, w0, acc0, 0, 0, 0);
        acc1 = __builtin_amdgcn_mfma_i32_32x32x32_i8(a, w1, acc1, 0, 0, 0);
    }
    k2_epilogue(acc0, lrow,      wave, kh, b0, b2, g2, be2, m2, v2, act2);
    k2_epilogue(acc1, 32 + lrow, wave, kh, b0, b2, g2, be2, m2, v2, act2);
}

// K3: fc1 as MFMA i8 GEMM 2048x1024x2304. Wave tile 32x64, K-split x2, 4 waves/block.
// A = act2 [2048][2304], B = wf1s [1024][2304] (both natural layout).
__global__ __launch_bounds__(256) void k3_mfma(
        const signed char* __restrict__ act2, const signed char* __restrict__ wf1s,
        const float* __restrict__ bf1, const float* __restrict__ gf1,
        const float* __restrict__ bef1, const float* __restrict__ mf1,
        const float* __restrict__ vf1, signed char* __restrict__ act3) {
    __shared__ int red[2][2048];
    int tid = threadIdx.x;
    int l = tid & 63, w = tid >> 6;
    int tile_local = w >> 1, khalf = w & 1;
    int tile = blockIdx.x * 2 + tile_local;       // 0..1023
    int tn = tile & 15, tm = tile >> 4;           // tn: N/64, tm: M/32
    int lrow = l & 31, kh = l >> 5;

    const signed char* aptr = act2 + (size_t)(tm * 32 + lrow) * 2304 + khalf * 1152 + kh * 16;
    const signed char* bptr = wf1s + (size_t)(tn * 64 + lrow) * 2304 + khalf * 1152 + kh * 16;

    i32x16 acc0 = {0};
    i32x16 acc1 = {0};
#pragma unroll 6
    for (int ks = 0; ks < 36; ++ks) {
        i32x4 a  = *(const i32x4*)(aptr + ks * 32);
        i32x4 b0 = *(const i32x4*)(bptr + ks * 32);
        i32x4 b1 = *(const i32x4*)(bptr + 32 * 2304 + ks * 32);
        acc0 = __builtin_amdgcn_mfma_i32_32x32x32_i8(a, b0, acc0, 0, 0, 0);
        acc1 = __builtin_amdgcn_mfma_i32_32x32x32_i8(a, b1, acc1, 0, 0, 0);
    }
    if (khalf) {
        int* rp = &red[tile_local][0];
#pragma unroll
        for (int r = 0; r < 16; r++) rp[r * 64 + l] = acc0[r];
#pragma unroll
        for (int r = 0; r < 16; r++) rp[(r + 16) * 64 + l] = acc1[r];
    }
    __syncthreads();
    if (!khalf) {
        const int* rp = &red[tile_local][0];
#pragma unroll
        for (int r = 0; r < 16; r++) acc0[r] += rp[r * 64 + l];
#pragma unroll
        for (int r = 0; r < 16; r++) acc1[r] += rp[(r + 16) * 64 + l];

        int col0 = tn * 64 + lrow;
        int col1 = col0 + 32;
        float bi0 = bf1[col0], m0 = mf1[col0];
        float sc0 = gf1[col0] / sqrtf(vf1[col0] + 1e-5f), bb0 = bef1[col0];
        float bi1 = bf1[col1], m1 = mf1[col1];
        float sc1 = gf1[col1] / sqrtf(vf1[col1] + 1e-5f), bb1 = bef1[col1];
#pragma unroll
        for (int r = 0; r < 16; r++) {
            int row = tm * 32 + (r & 3) + 8 * (r >> 2) + 4 * kh;
            float bn0 = ((float)acc0[r] + bi0 - m0) * sc0 + bb0;
            float bn1 = ((float)acc1[r] + bi1 - m1) * sc1 + bb1;
            act3[(size_t)row * 1024 + col0] = (signed char)fsign(bn0);
            act3[(size_t)row * 1024 + col1] = (signed char)fsign(bn1);
        }
    }
}

// K4: fc2 (1024->10) + bias + BN + log_softmax. One wave per image.
__global__ void k4_fc2(const signed char* __restrict__ act3, const signed char* __restrict__ swf2,
                       const float* __restrict__ bf2, const float* __restrict__ gf2,
                       const float* __restrict__ bef2, const float* __restrict__ mf2,
                       const float* __restrict__ vf2, float* __restrict__ out) {
    int wid = (blockIdx.x * 256 + threadIdx.x) >> 6;
    int lane = threadIdx.x & 63;
    if (wid >= BATCH) return;
    const int* hd = (const int*)act3 + (size_t)wid * 256;
    const int* wd = (const int*)swf2;
    int acc[10];
#pragma unroll
    for (int o = 0; o < 10; o++) acc[o] = 0;
#pragma unroll
    for (int i = 0; i < 4; i++) {
        int k4 = i * 64 + lane;
        int hv = hd[k4];
#pragma unroll
        for (int o = 0; o < 10; o++)
            acc[o] = sdot4(hv, wd[o * 256 + k4], acc[o]);
    }
#pragma unroll
    for (int o = 0; o < 10; o++)
#pragma unroll
        for (int s = 32; s > 0; s >>= 1) acc[o] += __shfl_xor(acc[o], s);
    if (lane == 0) {
        float logit[10];
        float mx = -1e30f;
#pragma unroll
        for (int o = 0; o < 10; o++) {
            float z = (float)acc[o] + bf2[o];
            float bn = (z - mf2[o]) * (gf2[o] / sqrtf(vf2[o] + 1e-5f)) + bef2[o];
            logit[o] = bn;
            mx = fmaxf(mx, bn);
        }
        float s = 0.f;
#pragma unroll
        for (int o = 0; o < 10; o++) s += expf(logit[o] - mx);
        float lse = mx + logf(s);
#pragma unroll
        for (int o = 0; o < 10; o++) out[(size_t)wid * 10 + o] = logit[o] - lse;
    }
}

extern "C" void kernel_launch(void* const* d_in, const int* in_sizes, int n_in,
                              void* d_out, int out_size, void* d_ws, size_t ws_size,
                              hipStream_t stream) {
    const float* x   = (const float*)d_in[0];
    const float* w1  = (const float*)d_in[1];
    const float* b1  = (const float*)d_in[2];
    const float* g1  = (const float*)d_in[3];
    const float* be1 = (const float*)d_in[4];
    const float* m1  = (const float*)d_in[5];
    const float* v1  = (const float*)d_in[6];
    const float* w2  = (const float*)d_in[7];
    const float* b2  = (const float*)d_in[8];
    const float* g2  = (const float*)d_in[9];
    const float* be2 = (const float*)d_in[10];
    const float* m2  = (const float*)d_in[11];
    const float* v2  = (const float*)d_in[12];
    const float* wf1 = (const float*)d_in[13];
    const float* bf1 = (const float*)d_in[14];
    const float* gf1 = (const float*)d_in[15];
    const float* bef1= (const float*)d_in[16];
    const float* mf1 = (const float*)d_in[17];
    const float* vf1 = (const float*)d_in[18];
    const float* wf2 = (const float*)d_in[19];
    const float* bf2 = (const float*)d_in[20];
    const float* gf2 = (const float*)d_in[21];
    const float* bef2= (const float*)d_in[22];
    const float* mf2 = (const float*)d_in[23];
    const float* vf2 = (const float*)d_in[24];
    float* out = (float*)d_out;

    // ws layout (all int8)
    char* ws = (char*)d_ws;
    signed char* act1 = (signed char*)ws;                  // 2048*169*32   = 11,075,584
    signed char* act2 = act1 + 11075584;                   // 2048*2304     =  4,718,592
    signed char* act3 = act2 + 4718592;                    // 2048*1024     =  2,097,152
    signed char* w2p  = act3 + 2097152;                    // 64*25*32      =     51,200
    signed char* wf1s = w2p + 51200;                       // 1024*2304     =  2,359,296
    signed char* wf2p = wf1s + 2359296;                    // 10*1024       =     10,240

    pack_w2_k<<<200, 256, 0, stream>>>(w2, w2p);
    binarize_k<<<9216, 256, 0, stream>>>(wf1, wf1s, 2359296);
    binarize_k<<<40, 256, 0, stream>>>(wf2, wf2p, 10240);

    k1_conv1<<<1352, 256, 0, stream>>>(x, w1, b1, g1, be1, m1, v1, act1);

    k2_mfma<<<1024, 576, 0, stream>>>(act1, w2p, b2, g2, be2, m2, v2, act2);

    k3_mfma<<<512, 256, 0, stream>>>(act2, wf1s, bf1, gf1, bef1, mf1, vf1, act3);

    k4_fc2<<<512, 256, 0, stream>>>(act3, wf2p, bf2, gf2, bef2, mf2, vf2, out);
}

// Round 6
// 132.105 us; speedup vs baseline: 28.0810x; 1.1071x over previous
//
#include <hip/hip_runtime.h>
#include <math.h>

#define BATCH 2048

typedef __attribute__((ext_vector_type(4))) int i32x4;
typedef __attribute__((ext_vector_type(16))) int i32x16;
typedef __attribute__((ext_vector_type(4))) float f32x4;

__device__ __forceinline__ int sdot4(int a, int b, int c) {
    return __builtin_amdgcn_sdot4(a, b, c, false);
}

__device__ __forceinline__ float fsign(float v) {
    return v > 0.f ? 1.f : (v < 0.f ? -1.f : 0.f);
}

__global__ void binarize_k(const float* __restrict__ w, signed char* __restrict__ o, int n) {
    int i = blockIdx.x * 256 + threadIdx.x;
    if (i < n) {
        float v = w[i];
        o[i] = v > 0.f ? 1 : (v < 0.f ? -1 : 0);
    }
}

// w2 [64][32][5][5] -> w2p [64][25][32] int8 (sign)
__global__ void pack_w2_k(const float* __restrict__ w2, signed char* __restrict__ w2p) {
    int i = blockIdx.x * 256 + threadIdx.x;  // 51200
    int ic = i % 32, tap = (i / 32) % 25, oc = i / 800;
    float v = w2[(oc * 32 + ic) * 25 + tap];
    w2p[i] = v > 0.f ? 1 : (v < 0.f ? -1 : 0);
}

// K1: conv1 + bias + BN + sign + pool2 -> act1 channel-last [B][13][13][32] int8
// One thread per (b, oc, pool-row py). Setup once, 13 cells streamed from regs.
__global__ __launch_bounds__(256) void k1_conv1(
        const float* __restrict__ x, const float* __restrict__ w1,
        const float* __restrict__ b1, const float* __restrict__ g1,
        const float* __restrict__ be1, const float* __restrict__ m1,
        const float* __restrict__ v1, signed char* __restrict__ act1) {
    int t = blockIdx.x * 256 + threadIdx.x;  // 2048*13*32 = 851,968 exact
    int oc = t & 31;
    int r = t >> 5;            // b*13 + py
    int py = r % 13, b = r / 13;

    float sw[9];
#pragma unroll
    for (int i = 0; i < 9; i++) sw[i] = fsign(w1[oc * 9 + i]);
    float bias = b1[oc], m = m1[oc];
    float sc = g1[oc] / sqrtf(v1[oc] + 1e-5f), bb = be1[oc];

    const float* xb = x + b * 784 + (2 * py) * 28;  // rows 2py..2py+3 used
    signed char ob[13];
    f32x4 ra[4][4];  // 4 rows x 16 cols, reused for both phases

    // ---- phase A: cols 0..15, pool cols px 0..6 ----
#pragma unroll
    for (int dy = 0; dy < 4; dy++)
#pragma unroll
        for (int c4 = 0; c4 < 4; c4++)
            ra[dy][c4] = *(const f32x4*)(xb + dy * 28 + c4 * 4);
#pragma unroll
    for (int px = 0; px < 7; px++) {
        float best = -2.f;
#pragma unroll
        for (int q = 0; q < 4; q++) {
            int dyp = q >> 1, dxp = q & 1;
            float acc = 0.f;
#pragma unroll
            for (int ky = 0; ky < 3; ky++)
#pragma unroll
                for (int kx = 0; kx < 3; kx++) {
                    int c = 2 * px + dxp + kx;
                    acc += ra[dyp + ky][c >> 2][c & 3] * sw[ky * 3 + kx];
                }
            float bn = (acc + bias - m) * sc + bb;
            best = fmaxf(best, fsign(bn));
        }
        ob[px] = (signed char)best;
    }
    // ---- phase B: cols 12..27, pool cols px 7..12 ----
#pragma unroll
    for (int dy = 0; dy < 4; dy++)
#pragma unroll
        for (int c4 = 0; c4 < 4; c4++)
            ra[dy][c4] = *(const f32x4*)(xb + dy * 28 + 12 + c4 * 4);
#pragma unroll
    for (int px = 7; px < 13; px++) {
        float best = -2.f;
#pragma unroll
        for (int q = 0; q < 4; q++) {
            int dyp = q >> 1, dxp = q & 1;
            float acc = 0.f;
#pragma unroll
            for (int ky = 0; ky < 3; ky++)
#pragma unroll
                for (int kx = 0; kx < 3; kx++) {
                    int c = 2 * px + dxp + kx - 12;
                    acc += ra[dyp + ky][c >> 2][c & 3] * sw[ky * 3 + kx];
                }
            float bn = (acc + bias - m) * sc + bb;
            best = fmaxf(best, fsign(bn));
        }
        ob[px] = (signed char)best;
    }

    signed char* dst = act1 + ((size_t)(b * 169) + py * 13) * 32 + oc;
#pragma unroll
    for (int px = 0; px < 13; px++) dst[px * 32] = ob[px];
}

// K2: conv2 as implicit-GEMM MFMA i8. Block = 2 images, 9 waves.
#define K2_IMG_STRIDE 9248          // 17*17*32
#define K2_WOFF 18496               // 2*9248
__device__ __forceinline__ void k2_epilogue(i32x16 A, int oc, int wave, int kh, int b0,
                                            const float* __restrict__ b2,
                                            const float* __restrict__ g2,
                                            const float* __restrict__ be2,
                                            const float* __restrict__ m2,
                                            const float* __restrict__ v2,
                                            signed char* __restrict__ act2) {
    float bias = b2[oc], mm = m2[oc];
    float sc = g2[oc] / sqrtf(v2[oc] + 1e-5f), bb = be2[oc];
#pragma unroll
    for (int g = 0; g < 4; g++) {
        int qo = wave * 8 + kh + 2 * g;      // 0..71 pool cell (2 images)
        int imo = qo / 36, qqo = qo - imo * 36;
        float best = -2.f;
#pragma unroll
        for (int jj = 0; jj < 4; jj++) {     // 4 pool partners live in reg quad
            float z = (float)A[g * 4 + jj] + bias;
            float bn = (z - mm) * sc + bb;
            best = fmaxf(best, fsign(bn));
        }
        act2[((size_t)(b0 + imo) * 64 + oc) * 36 + qqo] = (signed char)best;
    }
}

__global__ __launch_bounds__(576) void k2_mfma(
        const signed char* __restrict__ act1, const signed char* __restrict__ w2p,
        const float* __restrict__ b2, const float* __restrict__ g2,
        const float* __restrict__ be2, const float* __restrict__ m2,
        const float* __restrict__ v2, signed char* __restrict__ act2) {
    __shared__ __align__(16) signed char smem[69696];  // 18496 + 51200
    int tid = threadIdx.x;
    int b0 = blockIdx.x * 2;
    i32x4* s4 = (i32x4*)smem;
    i32x4 z4 = {0, 0, 0, 0};
    for (int i = tid; i < 1156; i += 576) s4[i] = z4;
    __syncthreads();
    {
        const i32x4* src = (const i32x4*)(act1 + (size_t)b0 * 5408);
        for (int i = tid; i < 676; i += 576) {
            int im = i / 338, r = i - im * 338;
            int pix = r >> 1, half = r & 1;
            int yy = pix / 13 + 2, xx = pix % 13 + 2;
            *(i32x4*)(smem + im * K2_IMG_STRIDE + (yy * 17 + xx) * 32 + half * 16) = src[i];
        }
        const i32x4* wsrc = (const i32x4*)w2p;
        for (int i = tid; i < 3200; i += 576) {
            int oc = i / 50, r = i - oc * 50;
            int tap = r >> 1, half = r & 1;
            *(i32x4*)(smem + K2_WOFF + tap * 2048 + oc * 32 + half * 16) = wsrc[i];
        }
    }
    __syncthreads();

    int wave = tid >> 6, lane = tid & 63;
    int lrow = lane & 31, kh = lane >> 5;
    int m = wave * 32 + lrow;
    int q = m >> 2, j = m & 3;
    int img = q / 36, qq = q - img * 36;
    int oy = 2 * (qq / 6) + (j >> 1);
    int ox = 2 * (qq - (qq / 6) * 6) + (j & 1);
    const signed char* abase = smem + img * K2_IMG_STRIDE + (oy * 17 + ox) * 32 + kh * 16;
    const signed char* bbase = smem + K2_WOFF + lrow * 32 + kh * 16;

    i32x16 acc0 = {0};
    i32x16 acc1 = {0};
#pragma unroll 5
    for (int tap = 0; tap < 25; ++tap) {
        int ky = tap / 5, kx = tap - (tap / 5) * 5;
        i32x4 a = *(const i32x4*)(abase + (ky * 17 + kx) * 32);
        i32x4 w0 = *(const i32x4*)(bbase + tap * 2048);
        i32x4 w1 = *(const i32x4*)(bbase + tap * 2048 + 1024);
        acc0 = __builtin_amdgcn_mfma_i32_32x32x32_i8(a, w0, acc0, 0, 0, 0);
        acc1 = __builtin_amdgcn_mfma_i32_32x32x32_i8(a, w1, acc1, 0, 0, 0);
    }
    k2_epilogue(acc0, lrow,      wave, kh, b0, b2, g2, be2, m2, v2, act2);
    k2_epilogue(acc1, 32 + lrow, wave, kh, b0, b2, g2, be2, m2, v2, act2);
}

// K3: fc1 as MFMA i8 GEMM 2048x1024x2304. Wave tile 32x64, K-split x2, 4 waves/block.
__global__ __launch_bounds__(256) void k3_mfma(
        const signed char* __restrict__ act2, const signed char* __restrict__ wf1s,
        const float* __restrict__ bf1, const float* __restrict__ gf1,
        const float* __restrict__ bef1, const float* __restrict__ mf1,
        const float* __restrict__ vf1, signed char* __restrict__ act3) {
    __shared__ int red[2][2048];
    int tid = threadIdx.x;
    int l = tid & 63, w = tid >> 6;
    int tile_local = w >> 1, khalf = w & 1;
    int tile = blockIdx.x * 2 + tile_local;       // 0..1023
    int tn = tile & 15, tm = tile >> 4;           // tn: N/64, tm: M/32
    int lrow = l & 31, kh = l >> 5;

    const signed char* aptr = act2 + (size_t)(tm * 32 + lrow) * 2304 + khalf * 1152 + kh * 16;
    const signed char* bptr = wf1s + (size_t)(tn * 64 + lrow) * 2304 + khalf * 1152 + kh * 16;

    i32x16 acc0 = {0};
    i32x16 acc1 = {0};
#pragma unroll 6
    for (int ks = 0; ks < 36; ++ks) {
        i32x4 a  = *(const i32x4*)(aptr + ks * 32);
        i32x4 b0 = *(const i32x4*)(bptr + ks * 32);
        i32x4 b1 = *(const i32x4*)(bptr + 32 * 2304 + ks * 32);
        acc0 = __builtin_amdgcn_mfma_i32_32x32x32_i8(a, b0, acc0, 0, 0, 0);
        acc1 = __builtin_amdgcn_mfma_i32_32x32x32_i8(a, b1, acc1, 0, 0, 0);
    }
    if (khalf) {
        int* rp = &red[tile_local][0];
#pragma unroll
        for (int r = 0; r < 16; r++) rp[r * 64 + l] = acc0[r];
#pragma unroll
        for (int r = 0; r < 16; r++) rp[(r + 16) * 64 + l] = acc1[r];
    }
    __syncthreads();
    if (!khalf) {
        const int* rp = &red[tile_local][0];
#pragma unroll
        for (int r = 0; r < 16; r++) acc0[r] += rp[r * 64 + l];
#pragma unroll
        for (int r = 0; r < 16; r++) acc1[r] += rp[(r + 16) * 64 + l];

        int col0 = tn * 64 + lrow;
        int col1 = col0 + 32;
        float bi0 = bf1[col0], m0 = mf1[col0];
        float sc0 = gf1[col0] / sqrtf(vf1[col0] + 1e-5f), bb0 = bef1[col0];
        float bi1 = bf1[col1], m1 = mf1[col1];
        float sc1 = gf1[col1] / sqrtf(vf1[col1] + 1e-5f), bb1 = bef1[col1];
#pragma unroll
        for (int r = 0; r < 16; r++) {
            int row = tm * 32 + (r & 3) + 8 * (r >> 2) + 4 * kh;
            float bn0 = ((float)acc0[r] + bi0 - m0) * sc0 + bb0;
            float bn1 = ((float)acc1[r] + bi1 - m1) * sc1 + bb1;
            act3[(size_t)row * 1024 + col0] = (signed char)fsign(bn0);
            act3[(size_t)row * 1024 + col1] = (signed char)fsign(bn1);
        }
    }
}

// K4: fc2 (1024->10) + bias + BN + log_softmax. One wave per image.
__global__ void k4_fc2(const signed char* __restrict__ act3, const signed char* __restrict__ swf2,
                       const float* __restrict__ bf2, const float* __restrict__ gf2,
                       const float* __restrict__ bef2, const float* __restrict__ mf2,
                       const float* __restrict__ vf2, float* __restrict__ out) {
    int wid = (blockIdx.x * 256 + threadIdx.x) >> 6;
    int lane = threadIdx.x & 63;
    if (wid >= BATCH) return;
    const int* hd = (const int*)act3 + (size_t)wid * 256;
    const int* wd = (const int*)swf2;
    int acc[10];
#pragma unroll
    for (int o = 0; o < 10; o++) acc[o] = 0;
#pragma unroll
    for (int i = 0; i < 4; i++) {
        int k4 = i * 64 + lane;
        int hv = hd[k4];
#pragma unroll
        for (int o = 0; o < 10; o++)
            acc[o] = sdot4(hv, wd[o * 256 + k4], acc[o]);
    }
#pragma unroll
    for (int o = 0; o < 10; o++)
#pragma unroll
        for (int s = 32; s > 0; s >>= 1) acc[o] += __shfl_xor(acc[o], s);
    if (lane == 0) {
        float logit[10];
        float mx = -1e30f;
#pragma unroll
        for (int o = 0; o < 10; o++) {
            float z = (float)acc[o] + bf2[o];
            float bn = (z - mf2[o]) * (gf2[o] / sqrtf(vf2[o] + 1e-5f)) + bef2[o];
            logit[o] = bn;
            mx = fmaxf(mx, bn);
        }
        float s = 0.f;
#pragma unroll
        for (int o = 0; o < 10; o++) s += expf(logit[o] - mx);
        float lse = mx + logf(s);
#pragma unroll
        for (int o = 0; o < 10; o++) out[(size_t)wid * 10 + o] = logit[o] - lse;
    }
}

extern "C" void kernel_launch(void* const* d_in, const int* in_sizes, int n_in,
                              void* d_out, int out_size, void* d_ws, size_t ws_size,
                              hipStream_t stream) {
    const float* x   = (const float*)d_in[0];
    const float* w1  = (const float*)d_in[1];
    const float* b1  = (const float*)d_in[2];
    const float* g1  = (const float*)d_in[3];
    const float* be1 = (const float*)d_in[4];
    const float* m1  = (const float*)d_in[5];
    const float* v1  = (const float*)d_in[6];
    const float* w2  = (const float*)d_in[7];
    const float* b2  = (const float*)d_in[8];
    const float* g2  = (const float*)d_in[9];
    const float* be2 = (const float*)d_in[10];
    const float* m2  = (const float*)d_in[11];
    const float* v2  = (const float*)d_in[12];
    const float* wf1 = (const float*)d_in[13];
    const float* bf1 = (const float*)d_in[14];
    const float* gf1 = (const float*)d_in[15];
    const float* bef1= (const float*)d_in[16];
    const float* mf1 = (const float*)d_in[17];
    const float* vf1 = (const float*)d_in[18];
    const float* wf2 = (const float*)d_in[19];
    const float* bf2 = (const float*)d_in[20];
    const float* gf2 = (const float*)d_in[21];
    const float* bef2= (const float*)d_in[22];
    const float* mf2 = (const float*)d_in[23];
    const float* vf2 = (const float*)d_in[24];
    float* out = (float*)d_out;

    // ws layout (all int8)
    char* ws = (char*)d_ws;
    signed char* act1 = (signed char*)ws;                  // 2048*169*32   = 11,075,584
    signed char* act2 = act1 + 11075584;                   // 2048*2304     =  4,718,592
    signed char* act3 = act2 + 4718592;                    // 2048*1024     =  2,097,152
    signed char* w2p  = act3 + 2097152;                    // 64*25*32      =     51,200
    signed char* wf1s = w2p + 51200;                       // 1024*2304     =  2,359,296
    signed char* wf2p = wf1s + 2359296;                    // 10*1024       =     10,240

    pack_w2_k<<<200, 256, 0, stream>>>(w2, w2p);
    binarize_k<<<9216, 256, 0, stream>>>(wf1, wf1s, 2359296);
    binarize_k<<<40, 256, 0, stream>>>(wf2, wf2p, 10240);

    k1_conv1<<<3328, 256, 0, stream>>>(x, w1, b1, g1, be1, m1, v1, act1);

    k2_mfma<<<1024, 576, 0, stream>>>(act1, w2p, b2, g2, be2, m2, v2, act2);

    k3_mfma<<<512, 256, 0, stream>>>(act2, wf1s, bf1, gf1, bef1, mf1, vf1, act3);

    k4_fc2<<<512, 256, 0, stream>>>(act3, wf2p, bf2, gf2, bef2, mf2, vf2, out);
}

// Round 7
// 107.263 us; speedup vs baseline: 34.5845x; 1.2316x over previous
//
#include <hip/hip_runtime.h>
#include <math.h>

#define BATCH 2048

typedef __attribute__((ext_vector_type(4))) int i32x4;
typedef __attribute__((ext_vector_type(16))) int i32x16;

__device__ __forceinline__ int sdot4(int a, int b, int c) {
    return __builtin_amdgcn_sdot4(a, b, c, false);
}

__device__ __forceinline__ float fsign(float v) {
    return v > 0.f ? 1.f : (v < 0.f ? -1.f : 0.f);
}

__global__ void binarize_k(const float* __restrict__ w, signed char* __restrict__ o, int n) {
    int i = blockIdx.x * 256 + threadIdx.x;
    if (i < n) {
        float v = w[i];
        o[i] = v > 0.f ? 1 : (v < 0.f ? -1 : 0);
    }
}

// w2 [64][32][5][5] -> w2p [64][25][32] int8 (sign)
__global__ void pack_w2_k(const float* __restrict__ w2, signed char* __restrict__ w2p) {
    int i = blockIdx.x * 256 + threadIdx.x;  // 51200
    int ic = i % 32, tap = (i / 32) % 25, oc = i / 800;
    float v = w2[(oc * 32 + ic) * 25 + tap];
    w2p[i] = v > 0.f ? 1 : (v < 0.f ? -1 : 0);
}

// per-oc conv1 constants: [32][16] = {sw0..8, bias, m, sc, bb, pad}
__global__ void prep_k1(const float* __restrict__ w1, const float* __restrict__ b1,
                        const float* __restrict__ g1, const float* __restrict__ be1,
                        const float* __restrict__ m1, const float* __restrict__ v1,
                        float* __restrict__ k1c) {
    int oc = threadIdx.x;
    if (oc < 32) {
        for (int i = 0; i < 9; i++) k1c[oc * 16 + i] = fsign(w1[oc * 9 + i]);
        k1c[oc * 16 + 9] = b1[oc];
        k1c[oc * 16 + 10] = m1[oc];
        k1c[oc * 16 + 11] = g1[oc] / sqrtf(v1[oc] + 1e-5f);
        k1c[oc * 16 + 12] = be1[oc];
    }
}

// K1: conv1 + bias + BN + sign + pool2 -> act1 channel-last [B][13][13][32] int8
// One thread per (b, pool cell); oc-loop is wave-uniform -> consts in SGPRs.
__global__ __launch_bounds__(256) void k1_conv1(
        const float* __restrict__ x, const float* __restrict__ k1c,
        signed char* __restrict__ act1) {
    int t = blockIdx.x * 256 + threadIdx.x;  // 1352*256 = 2048*169 exact
    int pix = t % 169, b = t / 169;
    int py = pix / 13, px = pix % 13;
    const float* xb = x + b * 784 + (2 * py) * 28 + 2 * px;
    float xr[4][4];
#pragma unroll
    for (int dy = 0; dy < 4; dy++)
#pragma unroll
        for (int dx = 0; dx < 4; dx++) xr[dy][dx] = xb[dy * 28 + dx];
    int dws[8];
#pragma unroll
    for (int j = 0; j < 8; j++) {
        int dw = 0;
#pragma unroll
        for (int jj = 0; jj < 4; jj++) {
            int oc = j * 4 + jj;
            const float* c = k1c + oc * 16;   // wave-uniform -> scalar loads
            float best = -1e30f;
#pragma unroll
            for (int q = 0; q < 4; q++) {
                int dyp = q >> 1, dxp = q & 1;
                float acc = 0.f;
#pragma unroll
                for (int ky = 0; ky < 3; ky++)
#pragma unroll
                    for (int kx = 0; kx < 3; kx++)
                        acc += xr[dyp + ky][dxp + kx] * c[ky * 3 + kx];
                float bn = (acc + c[9] - c[10]) * c[11] + c[12];
                best = fmaxf(best, bn);   // sign(max) == max(sign): sign monotone
            }
            dw |= ((int)fsign(best) & 0xFF) << (8 * jj);
        }
        dws[j] = dw;
    }
    int4* dst = (int4*)(act1 + (size_t)t * 32);
    dst[0] = make_int4(dws[0], dws[1], dws[2], dws[3]);
    dst[1] = make_int4(dws[4], dws[5], dws[6], dws[7]);
}

// K2: conv2 as implicit-GEMM MFMA i8. Block = 2 images, 9 waves.
#define K2_IMG_STRIDE 9248          // 17*17*32
#define K2_WOFF 18496               // 2*9248
__device__ __forceinline__ void k2_epilogue(i32x16 A, int oc, int wave, int kh, int b0,
                                            const float* __restrict__ b2,
                                            const float* __restrict__ g2,
                                            const float* __restrict__ be2,
                                            const float* __restrict__ m2,
                                            const float* __restrict__ v2,
                                            signed char* __restrict__ act2) {
    float bias = b2[oc], mm = m2[oc];
    float sc = g2[oc] / sqrtf(v2[oc] + 1e-5f), bb = be2[oc];
#pragma unroll
    for (int g = 0; g < 4; g++) {
        int qo = wave * 8 + kh + 2 * g;      // 0..71 pool cell (2 images)
        int imo = qo / 36, qqo = qo - imo * 36;
        float best = -2.f;
#pragma unroll
        for (int jj = 0; jj < 4; jj++) {     // 4 pool partners live in reg quad
            float z = (float)A[g * 4 + jj] + bias;
            float bn = (z - mm) * sc + bb;
            best = fmaxf(best, fsign(bn));
        }
        act2[((size_t)(b0 + imo) * 64 + oc) * 36 + qqo] = (signed char)best;
    }
}

__global__ __launch_bounds__(576) void k2_mfma(
        const signed char* __restrict__ act1, const signed char* __restrict__ w2p,
        const float* __restrict__ b2, const float* __restrict__ g2,
        const float* __restrict__ be2, const float* __restrict__ m2,
        const float* __restrict__ v2, signed char* __restrict__ act2) {
    __shared__ __align__(16) signed char smem[69696];  // 18496 + 51200
    int tid = threadIdx.x;
    int b0 = blockIdx.x * 2;
    i32x4* s4 = (i32x4*)smem;
    i32x4 z4 = {0, 0, 0, 0};
    for (int i = tid; i < 1156; i += 576) s4[i] = z4;
    __syncthreads();
    {
        const i32x4* src = (const i32x4*)(act1 + (size_t)b0 * 5408);
        for (int i = tid; i < 676; i += 576) {
            int im = i / 338, r = i - im * 338;
            int pix = r >> 1, half = r & 1;
            int yy = pix / 13 + 2, xx = pix % 13 + 2;
            *(i32x4*)(smem + im * K2_IMG_STRIDE + (yy * 17 + xx) * 32 + half * 16) = src[i];
        }
        const i32x4* wsrc = (const i32x4*)w2p;
        for (int i = tid; i < 3200; i += 576) {
            int oc = i / 50, r = i - oc * 50;
            int tap = r >> 1, half = r & 1;
            *(i32x4*)(smem + K2_WOFF + tap * 2048 + oc * 32 + half * 16) = wsrc[i];
        }
    }
    __syncthreads();

    int wave = tid >> 6, lane = tid & 63;
    int lrow = lane & 31, kh = lane >> 5;
    int m = wave * 32 + lrow;
    int q = m >> 2, j = m & 3;
    int img = q / 36, qq = q - img * 36;
    int oy = 2 * (qq / 6) + (j >> 1);
    int ox = 2 * (qq - (qq / 6) * 6) + (j & 1);
    const signed char* abase = smem + img * K2_IMG_STRIDE + (oy * 17 + ox) * 32 + kh * 16;
    const signed char* bbase = smem + K2_WOFF + lrow * 32 + kh * 16;

    i32x16 acc0 = {0};
    i32x16 acc1 = {0};
#pragma unroll 5
    for (int tap = 0; tap < 25; ++tap) {
        int ky = tap / 5, kx = tap - (tap / 5) * 5;
        i32x4 a = *(const i32x4*)(abase + (ky * 17 + kx) * 32);
        i32x4 w0 = *(const i32x4*)(bbase + tap * 2048);
        i32x4 w1 = *(const i32x4*)(bbase + tap * 2048 + 1024);
        acc0 = __builtin_amdgcn_mfma_i32_32x32x32_i8(a, w0, acc0, 0, 0, 0);
        acc1 = __builtin_amdgcn_mfma_i32_32x32x32_i8(a, w1, acc1, 0, 0, 0);
    }
    k2_epilogue(acc0, lrow,      wave, kh, b0, b2, g2, be2, m2, v2, act2);
    k2_epilogue(acc1, 32 + lrow, wave, kh, b0, b2, g2, be2, m2, v2, act2);
}

// K3: fc1 as MFMA i8 GEMM 2048x1024x2304. Wave tile 32x64, K-split x2, 4 waves/block.
__global__ __launch_bounds__(256) void k3_mfma(
        const signed char* __restrict__ act2, const signed char* __restrict__ wf1s,
        const float* __restrict__ bf1, const float* __restrict__ gf1,
        const float* __restrict__ bef1, const float* __restrict__ mf1,
        const float* __restrict__ vf1, signed char* __restrict__ act3) {
    __shared__ int red[2][2048];
    int tid = threadIdx.x;
    int l = tid & 63, w = tid >> 6;
    int tile_local = w >> 1, khalf = w & 1;
    int tile = blockIdx.x * 2 + tile_local;       // 0..1023
    int tn = tile & 15, tm = tile >> 4;           // tn: N/64, tm: M/32
    int lrow = l & 31, kh = l >> 5;

    const signed char* aptr = act2 + (size_t)(tm * 32 + lrow) * 2304 + khalf * 1152 + kh * 16;
    const signed char* bptr = wf1s + (size_t)(tn * 64 + lrow) * 2304 + khalf * 1152 + kh * 16;

    i32x16 acc0 = {0};
    i32x16 acc1 = {0};
#pragma unroll 6
    for (int ks = 0; ks < 36; ++ks) {
        i32x4 a  = *(const i32x4*)(aptr + ks * 32);
        i32x4 b0 = *(const i32x4*)(bptr + ks * 32);
        i32x4 b1 = *(const i32x4*)(bptr + 32 * 2304 + ks * 32);
        acc0 = __builtin_amdgcn_mfma_i32_32x32x32_i8(a, b0, acc0, 0, 0, 0);
        acc1 = __builtin_amdgcn_mfma_i32_32x32x32_i8(a, b1, acc1, 0, 0, 0);
    }
    if (khalf) {
        int* rp = &red[tile_local][0];
#pragma unroll
        for (int r = 0; r < 16; r++) rp[r * 64 + l] = acc0[r];
#pragma unroll
        for (int r = 0; r < 16; r++) rp[(r + 16) * 64 + l] = acc1[r];
    }
    __syncthreads();
    if (!khalf) {
        const int* rp = &red[tile_local][0];
#pragma unroll
        for (int r = 0; r < 16; r++) acc0[r] += rp[r * 64 + l];
#pragma unroll
        for (int r = 0; r < 16; r++) acc1[r] += rp[(r + 16) * 64 + l];

        int col0 = tn * 64 + lrow;
        int col1 = col0 + 32;
        float bi0 = bf1[col0], m0 = mf1[col0];
        float sc0 = gf1[col0] / sqrtf(vf1[col0] + 1e-5f), bb0 = bef1[col0];
        float bi1 = bf1[col1], m1 = mf1[col1];
        float sc1 = gf1[col1] / sqrtf(vf1[col1] + 1e-5f), bb1 = bef1[col1];
#pragma unroll
        for (int r = 0; r < 16; r++) {
            int row = tm * 32 + (r & 3) + 8 * (r >> 2) + 4 * kh;
            float bn0 = ((float)acc0[r] + bi0 - m0) * sc0 + bb0;
            float bn1 = ((float)acc1[r] + bi1 - m1) * sc1 + bb1;
            act3[(size_t)row * 1024 + col0] = (signed char)fsign(bn0);
            act3[(size_t)row * 1024 + col1] = (signed char)fsign(bn1);
        }
    }
}

// K4: fc2 (1024->10) + bias + BN + log_softmax. One wave per image.
__global__ void k4_fc2(const signed char* __restrict__ act3, const signed char* __restrict__ swf2,
                       const float* __restrict__ bf2, const float* __restrict__ gf2,
                       const float* __restrict__ bef2, const float* __restrict__ mf2,
                       const float* __restrict__ vf2, float* __restrict__ out) {
    int wid = (blockIdx.x * 256 + threadIdx.x) >> 6;
    int lane = threadIdx.x & 63;
    if (wid >= BATCH) return;
    const int* hd = (const int*)act3 + (size_t)wid * 256;
    const int* wd = (const int*)swf2;
    int acc[10];
#pragma unroll
    for (int o = 0; o < 10; o++) acc[o] = 0;
#pragma unroll
    for (int i = 0; i < 4; i++) {
        int k4 = i * 64 + lane;
        int hv = hd[k4];
#pragma unroll
        for (int o = 0; o < 10; o++)
            acc[o] = sdot4(hv, wd[o * 256 + k4], acc[o]);
    }
#pragma unroll
    for (int o = 0; o < 10; o++)
#pragma unroll
        for (int s = 32; s > 0; s >>= 1) acc[o] += __shfl_xor(acc[o], s);
    if (lane == 0) {
        float logit[10];
        float mx = -1e30f;
#pragma unroll
        for (int o = 0; o < 10; o++) {
            float z = (float)acc[o] + bf2[o];
            float bn = (z - mf2[o]) * (gf2[o] / sqrtf(vf2[o] + 1e-5f)) + bef2[o];
            logit[o] = bn;
            mx = fmaxf(mx, bn);
        }
        float s = 0.f;
#pragma unroll
        for (int o = 0; o < 10; o++) s += expf(logit[o] - mx);
        float lse = mx + logf(s);
#pragma unroll
        for (int o = 0; o < 10; o++) out[(size_t)wid * 10 + o] = logit[o] - lse;
    }
}

extern "C" void kernel_launch(void* const* d_in, const int* in_sizes, int n_in,
                              void* d_out, int out_size, void* d_ws, size_t ws_size,
                              hipStream_t stream) {
    const float* x   = (const float*)d_in[0];
    const float* w1  = (const float*)d_in[1];
    const float* b1  = (const float*)d_in[2];
    const float* g1  = (const float*)d_in[3];
    const float* be1 = (const float*)d_in[4];
    const float* m1  = (const float*)d_in[5];
    const float* v1  = (const float*)d_in[6];
    const float* w2  = (const float*)d_in[7];
    const float* b2  = (const float*)d_in[8];
    const float* g2  = (const float*)d_in[9];
    const float* be2 = (const float*)d_in[10];
    const float* m2  = (const float*)d_in[11];
    const float* v2  = (const float*)d_in[12];
    const float* wf1 = (const float*)d_in[13];
    const float* bf1 = (const float*)d_in[14];
    const float* gf1 = (const float*)d_in[15];
    const float* bef1= (const float*)d_in[16];
    const float* mf1 = (const float*)d_in[17];
    const float* vf1 = (const float*)d_in[18];
    const float* wf2 = (const float*)d_in[19];
    const float* bf2 = (const float*)d_in[20];
    const float* gf2 = (const float*)d_in[21];
    const float* bef2= (const float*)d_in[22];
    const float* mf2 = (const float*)d_in[23];
    const float* vf2 = (const float*)d_in[24];
    float* out = (float*)d_out;

    // ws layout (all int8 unless noted)
    char* ws = (char*)d_ws;
    signed char* act1 = (signed char*)ws;                  // 2048*169*32   = 11,075,584
    signed char* act2 = act1 + 11075584;                   // 2048*2304     =  4,718,592
    signed char* act3 = act2 + 4718592;                    // 2048*1024     =  2,097,152
    signed char* w2p  = act3 + 2097152;                    // 64*25*32      =     51,200
    signed char* wf1s = w2p + 51200;                       // 1024*2304     =  2,359,296
    signed char* wf2p = wf1s + 2359296;                    // 10*1024       =     10,240
    float* k1c = (float*)(wf2p + 10240);                   // 32*16 floats  =      2,048 B

    prep_k1<<<1, 64, 0, stream>>>(w1, b1, g1, be1, m1, v1, k1c);
    pack_w2_k<<<200, 256, 0, stream>>>(w2, w2p);
    binarize_k<<<9216, 256, 0, stream>>>(wf1, wf1s, 2359296);
    binarize_k<<<40, 256, 0, stream>>>(wf2, wf2p, 10240);

    k1_conv1<<<1352, 256, 0, stream>>>(x, k1c, act1);

    k2_mfma<<<1024, 576, 0, stream>>>(act1, w2p, b2, g2, be2, m2, v2, act2);

    k3_mfma<<<512, 256, 0, stream>>>(act2, wf1s, bf1, gf1, bef1, mf1, vf1, act3);

    k4_fc2<<<512, 256, 0, stream>>>(act3, wf2p, bf2, gf2, bef2, mf2, vf2, out);
}